// Round 6
// baseline (87.433 us; speedup 1.0000x reference)
//
#include <hip/hip_runtime.h>

// TotalVariation over [32,8,3,256,256] f32 = 768 images of 256x256.
// tv = (sum|dh+eps| + sum|dw+eps|) / N, N = 50331648.
//
// Each 64-lane wave owns a 32-row strip of one image; a row is exactly
// 64 float4s -> one wave-wide coalesced 1KB load per row. Walking down
// keeps the previous row in registers (vertical diffs need no re-load);
// the cross-float4 horizontal diff comes from __shfl_down. Branch-free
// inner loop, unroll 4 (unroll 8 regressed: occupancy). Single-pass
// reduction: blocks write partials, last-arriving block (counter in ws,
// zeroed by a 4B memset node) reduces them and writes d_out.

#define EPS 1e-6f

static constexpr long long NTOT = 32LL * 8 * 3 * 256 * 256;  // 50,331,648
static constexpr int RPS    = 32;                  // rows per strip
static constexpr int STRIPS = 768 * (256 / RPS);   // 6144
static constexpr int WPB    = 4;                   // waves per block
static constexpr int BLOCKS = STRIPS / WPB;        // 1536

__global__ void __launch_bounds__(256)
tv_strip_kernel(const float* __restrict__ x, double* __restrict__ partial,
                unsigned int* __restrict__ count, float* __restrict__ out) {
    const int wid   = threadIdx.x >> 6;
    const int lane  = threadIdx.x & 63;
    const int strip = blockIdx.x * WPB + wid;        // 0 .. 6143
    const int img   = strip >> 3;                    // 8 strips per image
    const int r0    = (strip & 7) << 5;              // first row of strip

    const float* p = x + (size_t)img * 65536 + (size_t)r0 * 256 + lane * 4;

    float acc = 0.0f;
    float4 a = *reinterpret_cast<const float4*>(p);

    // rows r0+1 .. r0+31 are always inside the image: branch-free body.
    #pragma unroll 4
    for (int k = 1; k < RPS; ++k) {
        const float4 b = *reinterpret_cast<const float4*>(p + k * 256);
        // horizontal diffs for row r0+k-1
        acc += fabsf(a.y - a.x + EPS);
        acc += fabsf(a.z - a.y + EPS);
        acc += fabsf(a.w - a.z + EPS);
        const float nx = __shfl_down(a.x, 1, 64);    // neighbor float4's .x
        if (lane < 63) acc += fabsf(nx - a.w + EPS); // lane 63 = row end
        // vertical diffs row r0+k-1 -> r0+k
        acc += fabsf(b.x - a.x + EPS);
        acc += fabsf(b.y - a.y + EPS);
        acc += fabsf(b.z - a.z + EPS);
        acc += fabsf(b.w - a.w + EPS);
        a = b;
    }

    // epilogue: last row of the strip (r0+31)
    acc += fabsf(a.y - a.x + EPS);
    acc += fabsf(a.z - a.y + EPS);
    acc += fabsf(a.w - a.z + EPS);
    {
        const float nx = __shfl_down(a.x, 1, 64);
        if (lane < 63) acc += fabsf(nx - a.w + EPS);
    }
    // vertical diff into the next strip's first row, unless this is the
    // image's last strip (wave-uniform branch, executed once).
    if (r0 < 256 - RPS) {
        const float4 b = *reinterpret_cast<const float4*>(p + RPS * 256);
        acc += fabsf(b.x - a.x + EPS);
        acc += fabsf(b.y - a.y + EPS);
        acc += fabsf(b.z - a.z + EPS);
        acc += fabsf(b.w - a.w + EPS);
    }

    // wave reduction
    #pragma unroll
    for (int off = 32; off > 0; off >>= 1)
        acc += __shfl_down(acc, off, 64);

    __shared__ double sdata[WPB];
    __shared__ bool amLast;
    if (lane == 0) sdata[wid] = (double)acc;
    __syncthreads();
    if (threadIdx.x == 0) {
        partial[blockIdx.x] = sdata[0] + sdata[1] + sdata[2] + sdata[3];
        __threadfence();                             // publish partial
        const unsigned int old = atomicAdd(count, 1u);
        amLast = (old == (unsigned int)(BLOCKS - 1));
    }
    __syncthreads();

    // last-arriving block reduces all partials and writes the output.
    if (amLast) {
        __threadfence();                             // acquire partials
        double s = 0.0;
        for (int i = threadIdx.x; i < BLOCKS; i += 256)
            s += partial[i];
        #pragma unroll
        for (int off = 32; off > 0; off >>= 1)
            s += __shfl_down(s, off, 64);
        __shared__ double sd[WPB];
        if (lane == 0) sd[wid] = s;
        __syncthreads();
        if (threadIdx.x == 0)
            out[0] = (float)((sd[0] + sd[1] + sd[2] + sd[3]) / (double)NTOT);
    }
}

extern "C" void kernel_launch(void* const* d_in, const int* in_sizes, int n_in,
                              void* d_out, int out_size, void* d_ws, size_t ws_size,
                              hipStream_t stream) {
    const float*  x       = (const float*)d_in[0];
    float*        out     = (float*)d_out;
    double*       partial = (double*)d_ws;                 // BLOCKS doubles
    unsigned int* count   = (unsigned int*)(partial + BLOCKS);

    hipMemsetAsync((void*)count, 0, sizeof(unsigned int), stream);  // 4 B
    tv_strip_kernel<<<BLOCKS, 256, 0, stream>>>(x, partial, count, out);
}

// Round 7
// 38.706 us; speedup vs baseline: 2.2589x; 2.2589x over previous
//
#include <hip/hip_runtime.h>

// TotalVariation over [32,8,3,256,256] f32 = 768 images of 256x256.
// tv = (sum|dh+eps| + sum|dw+eps|) / N, N = 50331648.
//
// Round-2 structure (proven fastest): strip kernel -> block partials,
// dependent 1-block finalize. RPS=64 halves strip-boundary duplicate
// reads vs RPS=32 (+1.6% traffic instead of +3.2%).
// DO NOT put device-scope atomics/__threadfence in the hot kernel:
// round-5 measured 1536 in-kernel fences collapsing BW to 711 GB/s
// (L2 invalidations during streaming -> latency-bound, 2.3x slower).

#define EPS 1e-6f

static constexpr long long NTOT = 32LL * 8 * 3 * 256 * 256;  // 50,331,648
static constexpr int RPS    = 64;                  // rows per strip
static constexpr int STRIPS = 768 * (256 / RPS);   // 3072
static constexpr int WPB    = 4;                   // waves per block
static constexpr int BLOCKS = STRIPS / WPB;        // 768 = 3 blocks/CU

__global__ void __launch_bounds__(256)
tv_strip_kernel(const float* __restrict__ x, double* __restrict__ partial) {
    const int wid   = threadIdx.x >> 6;
    const int lane  = threadIdx.x & 63;
    const int strip = blockIdx.x * WPB + wid;        // 0 .. 3071
    const int img   = strip >> 2;                    // 4 strips per image
    const int r0    = (strip & 3) << 6;              // first row of strip

    const float* p = x + (size_t)img * 65536 + (size_t)r0 * 256 + lane * 4;

    float acc = 0.0f;
    float4 a = *reinterpret_cast<const float4*>(p);

    // rows r0+1 .. r0+63 are always inside the image: branch-free body.
    #pragma unroll 4
    for (int k = 1; k < RPS; ++k) {
        const float4 b = *reinterpret_cast<const float4*>(p + k * 256);
        // horizontal diffs for row r0+k-1
        acc += fabsf(a.y - a.x + EPS);
        acc += fabsf(a.z - a.y + EPS);
        acc += fabsf(a.w - a.z + EPS);
        const float nx = __shfl_down(a.x, 1, 64);    // neighbor float4's .x
        if (lane < 63) acc += fabsf(nx - a.w + EPS); // lane 63 = row end
        // vertical diffs row r0+k-1 -> r0+k
        acc += fabsf(b.x - a.x + EPS);
        acc += fabsf(b.y - a.y + EPS);
        acc += fabsf(b.z - a.z + EPS);
        acc += fabsf(b.w - a.w + EPS);
        a = b;
    }

    // epilogue: last row of the strip (r0+63)
    acc += fabsf(a.y - a.x + EPS);
    acc += fabsf(a.z - a.y + EPS);
    acc += fabsf(a.w - a.z + EPS);
    {
        const float nx = __shfl_down(a.x, 1, 64);
        if (lane < 63) acc += fabsf(nx - a.w + EPS);
    }
    // vertical diff into the next strip's first row, unless this is the
    // image's last strip (wave-uniform branch, executed once).
    if (r0 < 256 - RPS) {
        const float4 b = *reinterpret_cast<const float4*>(p + RPS * 256);
        acc += fabsf(b.x - a.x + EPS);
        acc += fabsf(b.y - a.y + EPS);
        acc += fabsf(b.z - a.z + EPS);
        acc += fabsf(b.w - a.w + EPS);
    }

    // wave reduction
    #pragma unroll
    for (int off = 32; off > 0; off >>= 1)
        acc += __shfl_down(acc, off, 64);

    __shared__ double sdata[WPB];
    if (lane == 0) sdata[wid] = (double)acc;
    __syncthreads();
    if (threadIdx.x == 0)
        partial[blockIdx.x] = sdata[0] + sdata[1] + sdata[2] + sdata[3];
}

__global__ void __launch_bounds__(256)
tv_final_kernel(const double* __restrict__ partial, float* __restrict__ out) {
    double s = 0.0;
    for (int i = threadIdx.x; i < BLOCKS; i += 256)
        s += partial[i];
    #pragma unroll
    for (int off = 32; off > 0; off >>= 1)
        s += __shfl_down(s, off, 64);
    __shared__ double sd[4];
    const int wid  = threadIdx.x >> 6;
    const int lane = threadIdx.x & 63;
    if (lane == 0) sd[wid] = s;
    __syncthreads();
    if (threadIdx.x == 0)
        out[0] = (float)((sd[0] + sd[1] + sd[2] + sd[3]) / (double)NTOT);
}

extern "C" void kernel_launch(void* const* d_in, const int* in_sizes, int n_in,
                              void* d_out, int out_size, void* d_ws, size_t ws_size,
                              hipStream_t stream) {
    const float* x   = (const float*)d_in[0];
    float*       out = (float*)d_out;
    double*      ws  = (double*)d_ws;   // BLOCKS doubles = 6 KB of scratch

    tv_strip_kernel<<<BLOCKS, 256, 0, stream>>>(x, ws);
    tv_final_kernel<<<1, 256, 0, stream>>>(ws, out);
}